// Round 6
// baseline (49.857 us; speedup 1.0000x reference)
//
#include <hip/hip_runtime.h>
#include <hip/hip_bf16.h>

// Analytic reduction of the reference:
//   angles = pi*tanh(MLP(x));  <Z0> = sin(theta1)*sin(theta2)  (theta0, q_params cancel)
//   out = sigmoid(5*<Z0>)
// Memory-bound on streaming x (205 MB). Round 6: temporal burst grouping.
//   Theory: all prior rounds visit each 3136 B row 25x in 128 B nibbles ->
//   HBM row-activate bound (~4.5 TB/s). Now A-loads issue in 4-step groups:
//   512 B contiguous per row per burst, 8 loads back-to-back, double-grouped
//   (GA/GB, 64 VGPR) to stay under the 128-VGPR / 4-waves-per-SIMD budget.
//   Main loop stays barrier-free (B-frags from read-only LDS, A direct to reg).

#define KDIM 784
#define BMB 256
#define NSTEP 25          // 6 groups of 4 K-steps + tail step 24 (k=768..783)
#define H1STR 66          // h1 LDS stride (words): 2-way banks (free)

using f32x4 = __attribute__((ext_vector_type(4))) float;
using s16x8 = __attribute__((ext_vector_type(8))) short;

union LdsU {
    uint4 bfr[NSTEP * 4 * 64];            // 102400 B: W1 frags [step][n][lane]
    struct {
        float h1[BMB * H1STR];            // 67584 B
        float part[4][BMB][2];            // 8192 B
    } t;
};

__device__ __forceinline__ ushort f2bf(float f) {
    uint b = __float_as_uint(f);
    b += 0x7FFFu + ((b >> 16) & 1u);      // RNE
    return (ushort)(b >> 16);
}
__device__ __forceinline__ uint pack2(float lo, float hi) {
    return (uint)f2bf(lo) | ((uint)f2bf(hi) << 16);
}
__device__ __forceinline__ uint4 pack8(float4 a, float4 b) {
    return make_uint4(pack2(a.x, a.y), pack2(a.z, a.w),
                      pack2(b.x, b.y), pack2(b.z, b.w));
}
__device__ __forceinline__ s16x8 asfrag(uint4 p) {
    union { uint4 u; s16x8 s; } c; c.u = p; return c.s;
}

__global__ void __launch_bounds__(1024, 4) hybrid_kernel(
    const float* __restrict__ x, const float* __restrict__ W1,
    const float* __restrict__ b1, const float* __restrict__ W2,
    const float* __restrict__ b2, const float* __restrict__ W3,
    const float* __restrict__ b3, float* __restrict__ out, int B)
{
    __shared__ LdsU lds;
    const int tid  = threadIdx.x;
    const int wave = tid >> 6, lane = tid & 63;
    const int row0 = blockIdx.x * BMB;

    // A in frag layout: lane owns row (wave*16 + (lane&15)), k-slot (lane>>4)*8
    const int q = lane >> 4;
    int arow = row0 + wave * 16 + (lane & 15);
    arow = arow < B ? arow : B - 1;                  // B % 256 == 0 in practice
    const float* abase = x + (size_t)arow * KDIM + q * 8;

    float4 GA[8], GB[8];                             // parity groups (rule #20)

    // group g = K-steps 4g..4g+3: 8 back-to-back loads, 512 B/row burst
    auto loadG = [&](int g, float4 (&R)[8]) {
        #pragma unroll
        for (int s = 0; s < 4; ++s) {
            R[2 * s]     = *(const float4*)(abase + (4 * g + s) * 32);
            R[2 * s + 1] = *(const float4*)(abase + (4 * g + s) * 32 + 4);
        }
    };

    loadG(0, GA);                                    // in flight during prologue
    loadG(1, GB);

    // stage W1 -> LDS in B-frag order: chunk c = (step, n, lane16B)
    for (int c = tid; c < NSTEP * 4 * 64; c += 1024) {
        int s = c >> 8, n = (c >> 6) & 3, l = c & 63;
        int k0  = s * 32 + ((l >> 4) << 3);
        int col = n * 16 + (l & 15);
        float4 w0 = make_float4(0.f, 0.f, 0.f, 0.f), w1 = w0;
        if (k0 < KDIM) {                             // tail zero-fill (784%8==0)
            const float* p = W1 + (size_t)col * KDIM + k0;
            w0 = *(const float4*)p;
            w1 = *(const float4*)(p + 4);
        }
        lds.bfr[c] = pack8(w0, w1);
    }

    f32x4 acc[4];
    #pragma unroll
    for (int n = 0; n < 4; ++n)
        #pragma unroll
        for (int j = 0; j < 4; ++j) acc[n][j] = 0.f;

    // raw barrier: drain LDS writes only; GA/GB loads stay in flight
    asm volatile("s_waitcnt lgkmcnt(0)" ::: "memory");
    __builtin_amdgcn_s_barrier();
    __builtin_amdgcn_sched_barrier(0);

    #define STEPC(sid, u0, u1)                                                     \
        {                                                                          \
            s16x8 af = asfrag(pack8(u0, u1));                                      \
            const uint4* bp = &lds.bfr[(sid) * 256 + lane];                        \
            _Pragma("unroll")                                                      \
            for (int n = 0; n < 4; ++n)                                            \
                acc[n] = __builtin_amdgcn_mfma_f32_16x16x32_bf16(                  \
                    af, asfrag(bp[n * 64]), acc[n], 0, 0, 0);                      \
        }

    auto consumeG = [&](int g, float4 (&R)[8]) {
        #pragma unroll
        for (int s = 0; s < 4; ++s)
            STEPC(4 * g + s, R[2 * s], R[2 * s + 1]);
    };

    consumeG(0, GA); loadG(2, GA);
    consumeG(1, GB); loadG(3, GB);
    consumeG(2, GA); loadG(4, GA);
    consumeG(3, GB); loadG(5, GB);
    consumeG(4, GA);
    {   // tail step 24 (k=768..783): only lanes with q<2 carry data
        float4 z = make_float4(0.f, 0.f, 0.f, 0.f);
        GA[0] = z; GA[1] = z;
        if (q < 2) {
            GA[0] = *(const float4*)(abase + 768);
            GA[1] = *(const float4*)(abase + 772);
        }
    }
    consumeG(5, GB);
    STEPC(24, GA[0], GA[1]);
    #undef STEPC

    __syncthreads();                                 // B-frag reads done; reuse LDS

    // h1 = relu(acc + b1); C layout (m89): col = n*16+(lane&15), row = (lane>>4)*4+j
    #pragma unroll
    for (int n = 0; n < 4; ++n) {
        int c = n * 16 + (lane & 15);
        float bias = b1[c];
        #pragma unroll
        for (int j = 0; j < 4; ++j) {
            int r = wave * 16 + (lane >> 4) * 4 + j;
            lds.t.h1[r * H1STR + c] = fmaxf(acc[n][j] + bias, 0.f);
        }
    }
    __syncthreads();

    // layers 2+3: row = tid&255, jq = tid>>8
    {
        const int row = tid & 255, jq = tid >> 8;
        const float* h1p = &lds.t.h1[row * H1STR];
        float4 hv[16];
        #pragma unroll
        for (int k4 = 0; k4 < 16; ++k4) hv[k4] = *(const float4*)(h1p + k4 * 4);
        float a1 = 0.f, a2 = 0.f;
        #pragma unroll
        for (int jj = 0; jj < 4; ++jj) {
            int j2 = jq * 4 + jj;
            float s = b2[j2];
            #pragma unroll
            for (int k4 = 0; k4 < 16; ++k4) {
                const float4 w = *(const float4*)(W2 + j2 * 64 + k4 * 4);
                s = fmaf(hv[k4].x, w.x, s); s = fmaf(hv[k4].y, w.y, s);
                s = fmaf(hv[k4].z, w.z, s); s = fmaf(hv[k4].w, w.w, s);
            }
            s = fmaxf(s, 0.f);
            a1 = fmaf(s, W3[16 + j2], a1);
            a2 = fmaf(s, W3[32 + j2], a2);
        }
        lds.t.part[jq][row][0] = a1;
        lds.t.part[jq][row][1] = a2;
    }
    __syncthreads();

    if (tid < BMB) {
        int grow = row0 + tid;
        if (grow < B) {
            float a1 = b3[1] + lds.t.part[0][tid][0] + lds.t.part[1][tid][0]
                             + lds.t.part[2][tid][0] + lds.t.part[3][tid][0];
            float a2 = b3[2] + lds.t.part[0][tid][1] + lds.t.part[1][tid][1]
                             + lds.t.part[2][tid][1] + lds.t.part[3][tid][1];
            float t1 = 1.f - 2.f / (__expf(2.f * a1) + 1.f);   // tanh
            float t2 = 1.f - 2.f / (__expf(2.f * a2) + 1.f);
            const float PI = 3.14159265358979323846f;
            float z0 = __sinf(PI * t1) * __sinf(PI * t2);
            out[grow] = 1.f / (1.f + __expf(-5.f * z0));
        }
    }
}

extern "C" void kernel_launch(void* const* d_in, const int* in_sizes, int n_in,
                              void* d_out, int out_size, void* d_ws, size_t ws_size,
                              hipStream_t stream) {
    const float* x  = (const float*)d_in[0];
    const float* W1 = (const float*)d_in[1];
    const float* b1 = (const float*)d_in[2];
    const float* W2 = (const float*)d_in[3];
    const float* b2 = (const float*)d_in[4];
    const float* W3 = (const float*)d_in[5];
    const float* b3 = (const float*)d_in[6];
    // d_in[7] = q_params: unused (RZ phases cancel in |psi|^2)
    int B = in_sizes[0] / KDIM;
    int grid = (B + BMB - 1) / BMB;
    hybrid_kernel<<<grid, 1024, 0, stream>>>(x, W1, b1, W2, b2, W3, b3, (float*)d_out, B);
}